// Round 5
// baseline (483.780 us; speedup 1.0000x reference)
//
#include <hip/hip_runtime.h>
#include <cstdint>

#define NTOT 4096   // 2b rows
#define BHALF 2048  // b
#define D1 4096
#define D2 2048
#define TT 32       // 4096/128 tiles per dim
#define NTILES 528  // TT*(TT+1)/2

typedef __attribute__((ext_vector_type(4))) float f32x4;
typedef __attribute__((ext_vector_type(8))) int i32x8;

// async 16B global->LDS DMA (wave-uniform LDS base + lane*16 scatter)
__device__ __forceinline__ void glds16(const uint8_t* g, uint8_t* l) {
    __builtin_amdgcn_global_load_lds(
        (const __attribute__((address_space(1))) void*)(uintptr_t)g,
        (__attribute__((address_space(3))) void*)(uint32_t)(uintptr_t)l,
        16, 0, 0);
}

// e4m3fn decode (for colsum only; data never near NaN/448)
__device__ __forceinline__ float fp8dec(unsigned b) {
    unsigned e = (b >> 3) & 15u, m = b & 7u;
    float v = e ? __uint_as_float(((e + 120u) << 23) | (m << 20))
                : (float)m * 0.001953125f;   // subnormal: m * 2^-9
    return (b & 128u) ? -v : v;
}

// ---------------- prep: per-row sumsq (fp32) + fp8 e4m3 convert ----------------
// blocks 0..4095: matrix1 rows; 4096..8191: matrix2 rows.
// blocks 0/1 additionally zero the colsum arrays (stream-ordered before colsum).
__global__ void prep_kernel(const float* __restrict__ z1s, const float* __restrict__ z1t,
                            const float* __restrict__ z2s, const float* __restrict__ z2t,
                            float* __restrict__ sq1, float* __restrict__ sq2,
                            uint8_t* __restrict__ t1f8, uint8_t* __restrict__ t2f8,
                            float* __restrict__ s1, float* __restrict__ s2) {
    int bid = blockIdx.x;
    int tid = threadIdx.x;
    if (bid == 0) { for (int i = tid; i < 4096; i += 256) s1[i] = 0.f; }
    if (bid == 1) { for (int i = tid; i < 2048; i += 256) s2[i] = 0.f; }
    int which = bid >> 12;
    int row = bid & 4095;
    int d = which ? D2 : D1;
    const float* s_ = which ? z2s : z1s;
    const float* t_ = which ? z2t : z1t;
    const float* src = (row < BHALF) ? s_ + (size_t)row * d : t_ + (size_t)(row - BHALF) * d;
    uint8_t* dst = (which ? t2f8 : t1f8) + (size_t)row * d;
    float* sq = which ? sq2 : sq1;
    const float4* src4 = (const float4*)src;
    float a = 0.f;
    int n8 = d >> 3;
    for (int i = tid; i < n8; i += 256) {
        float4 v0 = src4[2 * i], v1 = src4[2 * i + 1];
        a += v0.x * v0.x + v0.y * v0.y + v0.z * v0.z + v0.w * v0.w;
        a += v1.x * v1.x + v1.y * v1.y + v1.z * v1.z + v1.w * v1.w;
        int w0 = __builtin_amdgcn_cvt_pk_fp8_f32(v0.x, v0.y, 0, 0);
        w0 = __builtin_amdgcn_cvt_pk_fp8_f32(v0.z, v0.w, w0, 1);
        int w1 = __builtin_amdgcn_cvt_pk_fp8_f32(v1.x, v1.y, 0, 0);
        w1 = __builtin_amdgcn_cvt_pk_fp8_f32(v1.z, v1.w, w1, 1);
        ((uint2*)dst)[i] = uint2{(unsigned)w0, (unsigned)w1};
    }
    for (int o = 32; o; o >>= 1) a += __shfl_down(a, o);
    __shared__ float sh[4];
    int lane = tid & 63, w = tid >> 6;
    if (lane == 0) sh[w] = a;
    __syncthreads();
    if (tid == 0) sq[row] = sh[0] + sh[1] + sh[2] + sh[3];
}

// ---------------- column sums from fp8 copies (bandwidth term only) ----------------
// blocks 0..31: matrix1 (4 colchunks x 8 row panels); 32..47: matrix2 (2 x 8)
__global__ void colsum_fp8_kernel(const uint8_t* __restrict__ t1f8,
                                  const uint8_t* __restrict__ t2f8,
                                  float* __restrict__ s1, float* __restrict__ s2) {
    int bid = blockIdx.x;
    int which = bid >= 32;
    int local = which ? bid - 32 : bid;
    int d = which ? D2 : D1;
    int colchunks = d >> 10;
    int cb = local % colchunks, rb = local / colchunks;
    const uint8_t* base = which ? t2f8 : t1f8;
    float* s = which ? s2 : s1;
    int col = (cb << 10) + threadIdx.x * 4;
    int r0 = rb * 512;
    float a0 = 0.f, a1 = 0.f, a2 = 0.f, a3 = 0.f;
    const uint8_t* p = base + (size_t)r0 * d + col;
    for (int r = 0; r < 512; ++r) {
        uchar4 u = *(const uchar4*)(p + (size_t)r * d);
        a0 += fp8dec(u.x); a1 += fp8dec(u.y); a2 += fp8dec(u.z); a3 += fp8dec(u.w);
    }
    atomicAdd(&s[col], a0); atomicAdd(&s[col + 1], a1);
    atomicAdd(&s[col + 2], a2); atomicAdd(&s[col + 3], a3);
}

// ---------------- finalize: bandwidth constants + loss bias ----------------
__global__ void finalize_kernel(const float* __restrict__ s1, const float* __restrict__ s2,
                                const float* __restrict__ sq1, const float* __restrict__ sq2,
                                float* __restrict__ acc, float* __restrict__ out) {
    int tid = threadIdx.x;
    float a1 = 0.f, a2 = 0.f, q1 = 0.f, q2 = 0.f;
    for (int i = tid; i < 4096; i += 256) { float v = s1[i]; a1 += v * v; q1 += sq1[i]; q2 += sq2[i]; }
    for (int i = tid; i < 2048; i += 256) { float v = s2[i]; a2 += v * v; }
    for (int o = 32; o; o >>= 1) {
        a1 += __shfl_down(a1, o); a2 += __shfl_down(a2, o);
        q1 += __shfl_down(q1, o); q2 += __shfl_down(q2, o);
    }
    __shared__ float sh[4][4];
    int lane = tid & 63, w = tid >> 6;
    if (lane == 0) { sh[0][w] = a1; sh[1][w] = a2; sh[2][w] = q1; sh[3][w] = q2; }
    __syncthreads();
    if (tid == 0) {
        double ss1 = (double)sh[0][0] + sh[0][1] + sh[0][2] + sh[0][3];
        double ss2 = (double)sh[1][0] + sh[1][1] + sh[1][2] + sh[1][3];
        double t1 = (double)sh[2][0] + sh[2][1] + sh[2][2] + sh[2][3];
        double t2 = (double)sh[3][0] + sh[3][1] + sh[3][2] + sh[3][3];
        double S1 = 2.0 * (double)NTOT * t1 - 2.0 * ss1;
        double S2 = 2.0 * (double)NTOT * t2 - 2.0 * ss2;
        const double L2E = 1.4426950408889634;
        double nn = (double)NTOT * (double)(NTOT - 1);
        acc[2] = (float)(nn * L2E / (4.0 * S1));
        acc[3] = (float)(nn * L2E / (4.0 * S2));
        out[0] = 2.0f / (float)(BHALF - 1);
    }
}

// ---------------- MX-fp8 GEMM loop: BK=128 bytes, 16x16x128 scaled MFMA ----------
// LDS: row-major [128 rows][128 B]. lane L stages row (L>>3), 16B chunk (L&7)
// => per-8-lane groups cover contiguous 128B global segments (coalesced DMA).
// Fragment: lane holds 32 consecutive k-bytes at k-offset quad*32 (one MX block
// of 32 => uniform scale 0x7F = 1.0 is exact).
__device__ __forceinline__ void gemm_loop_mx(const uint8_t* __restrict__ ga,
                                             const uint8_t* __restrict__ gb,
                                             int d, uint8_t* As, uint8_t* Bs,
                                             f32x4 (&acc)[4][4], int wv, int lane,
                                             int wm, int wn, int lm, int quad) {
    int rsub = lane >> 3;              // 0..7
    int ch = lane & 7;                 // 16B chunk within the 128B row-slab
    const uint8_t* gaL = ga + (size_t)(wv * 32 + rsub) * d + ch * 16;
    const uint8_t* gbL = gb + (size_t)(wv * 32 + rsub) * d + ch * 16;
    uint8_t* AsW = As + wv * 32 * 128;
    uint8_t* BsW = Bs + wv * 32 * 128;
    for (int k0 = 0; k0 < d; k0 += 128) {
        __syncthreads();
#pragma unroll
        for (int i = 0; i < 4; ++i) {
            glds16(gaL + ((size_t)i * 8 * d + k0), AsW + i * 8 * 128);
            glds16(gbL + ((size_t)i * 8 * d + k0), BsW + i * 8 * 128);
        }
        __syncthreads();
        union F { uint4 h[2]; i32x8 v; };
        F a[4];
#pragma unroll
        for (int mi = 0; mi < 4; ++mi) {
            const uint4* p = (const uint4*)&As[(wm * 64 + mi * 16 + lm) * 128 + quad * 32];
            a[mi].h[0] = p[0]; a[mi].h[1] = p[1];
        }
#pragma unroll
        for (int ni = 0; ni < 4; ++ni) {
            F b;
            const uint4* p = (const uint4*)&Bs[(wn * 64 + ni * 16 + lm) * 128 + quad * 32];
            b.h[0] = p[0]; b.h[1] = p[1];
#pragma unroll
            for (int mi = 0; mi < 4; ++mi)
                acc[mi][ni] = __builtin_amdgcn_mfma_scale_f32_16x16x128_f8f6f4(
                    a[mi].v, b.v, acc[mi][ni], 0, 0, 0, 0x7F7F7F7F, 0, 0x7F7F7F7F);
        }
    }
}

// ---------------- Gram kernel: 1056 blocks = 528 tiles x {GEMM1, GEMM2} ----------
// Compact supertile->XCD map (round-robin blockIdx%8 -> XCD): 6 off-diag 8x8
// supertile regions -> XCD 0..5, 2 diagonal pairs -> XCD 6..7.
__global__ __launch_bounds__(256, 4) void gram_kernel(
    const uint8_t* __restrict__ t1f8, const uint8_t* __restrict__ t2f8,
    float* __restrict__ G1, float* __restrict__ G2) {
    __shared__ alignas(16) uint8_t As[128 * 128];
    __shared__ alignas(16) uint8_t Bs[128 * 128];
    int lid = blockIdx.x;
    int lin = (lid & 7) * 132 + (lid >> 3);
    int ti, tj, which;
    if (lin < 768) {
        int r = lin >> 7, q = lin & 127;
        which = q & 1;
        int t = q >> 1, a = t >> 3, b = t & 7;
        const int si_t[6] = {0, 0, 0, 1, 1, 2};
        const int sj_t[6] = {1, 2, 3, 2, 3, 3};
        ti = si_t[r] * 8 + a; tj = sj_t[r] * 8 + b;
    } else {
        int m = lin - 768;
        int dd = m / 144, q = m % 144;
        which = q & 1;
        int t = q >> 1;
        int s = 2 * dd + (t >= 36 ? 1 : 0);
        int tl = t >= 36 ? t - 36 : t;
        int a = 0;
        while (tl >= 8 - a) { tl -= 8 - a; ++a; }
        ti = s * 8 + a; tj = s * 8 + a + tl;
    }
    int tcan = TT * ti - (ti * (ti - 1)) / 2 + (tj - ti);
    int i0 = ti * 128, j0 = tj * 128;
    int d = which ? D2 : D1;
    const uint8_t* base = which ? t2f8 : t1f8;
    float* G = (which ? G2 : G1) + (size_t)tcan * 16384;

    int tid = threadIdx.x, lane = tid & 63, wv = tid >> 6;
    int wm = wv >> 1, wn = wv & 1, lm = lane & 15, quad = lane >> 4;
    f32x4 acc[4][4] = {};
    gemm_loop_mx(base + (size_t)i0 * d, base + (size_t)j0 * d, d, As, Bs, acc,
                 wv, lane, wm, wn, lm, quad);
#pragma unroll
    for (int mi = 0; mi < 4; ++mi)
#pragma unroll
        for (int ni = 0; ni < 4; ++ni)
#pragma unroll
            for (int rr = 0; rr < 4; ++rr)
                G[(size_t)(wm * 64 + mi * 16 + quad * 4 + rr) * 128 + wn * 64 + ni * 16 + lm] =
                    acc[mi][ni][rr];
}

// ---------------- epilogue: read Grams, 5-kernel sum, product, weighted reduce ----
__global__ __launch_bounds__(256, 4) void epi_kernel(
    const float* __restrict__ G1, const float* __restrict__ G2,
    const float* __restrict__ sq1, const float* __restrict__ sq2,
    const float* __restrict__ cv, float* __restrict__ out) {
    __shared__ float sqi1[128], sqj1[128], sqi2[128], sqj2[128];
    __shared__ float red[4];
    int t = blockIdx.x;
    int ti = 0, r = t;
    while (r >= TT - ti) { r -= TT - ti; ++ti; }
    int tj = ti + r;
    int i0 = ti * 128, j0 = tj * 128;
    int tid = threadIdx.x;
    if (tid < 128) {
        sqi1[tid] = sq1[i0 + tid]; sqj1[tid] = sq1[j0 + tid];
        sqi2[tid] = sq2[i0 + tid]; sqj2[tid] = sq2[j0 + tid];
    }
    __syncthreads();
    float c1 = cv[0], c2 = cv[1];
    const float4* g1 = (const float4*)(G1 + (size_t)t * 16384);
    const float4* g2 = (const float4*)(G2 + (size_t)t * 16384);
    bool diag = (ti == tj);
    float local = 0.f;
#pragma unroll 4
    for (int it = 0; it < 16; ++it) {
        int e4 = it * 256 + tid;
        int row = e4 >> 5, col = (e4 & 31) * 4;
        float4 a = g1[e4], b = g2[e4];
        float si1 = sqi1[row], si2 = sqi2[row];
        float ax[4] = {a.x, a.y, a.z, a.w}, bx[4] = {b.x, b.y, b.z, b.w};
#pragma unroll
        for (int j = 0; j < 4; ++j) {
            float l2a = fmaxf(si1 + sqj1[col + j] - 2.f * ax[j], 0.f);
            float l2b = fmaxf(si2 + sqj2[col + j] - 2.f * bx[j], 0.f);
            float t1 = __builtin_amdgcn_exp2f(-l2a * c1);
            float k1 = t1; float u1 = t1 * t1; k1 += u1; u1 *= u1; k1 += u1; u1 *= u1; k1 += u1; u1 *= u1; k1 += u1;
            float t2 = __builtin_amdgcn_exp2f(-l2b * c2);
            float k2 = t2; float u2 = t2 * t2; k2 += u2; u2 *= u2; k2 += u2; u2 *= u2; k2 += u2; u2 *= u2; k2 += u2;
            float v = k1 * k2;
            if (diag && (row == col + j)) v = 0.f;
            local += v;
        }
    }
    for (int o = 32; o; o >>= 1) local += __shfl_down(local, o);
    int lane = tid & 63, wv = tid >> 6;
    if (lane == 0) red[wv] = local;
    __syncthreads();
    if (tid == 0) {
        bool same = (i0 < BHALF) == (j0 < BHALF);
        float w = same ? (1.0f / ((float)BHALF * (float)(BHALF - 1)))
                       : (-1.0f / ((float)BHALF * (float)BHALF));
        if (!diag) w *= 2.f;
        atomicAdd(out, (red[0] + red[1] + red[2] + red[3]) * w);
    }
}

// ---------------- fallback: fused dual-GEMM (ws too small for Gram buffers) ------
__global__ __launch_bounds__(256, 2) void jmmd_fused(
    const uint8_t* __restrict__ t1f8, const uint8_t* __restrict__ t2f8,
    const float* __restrict__ sq1, const float* __restrict__ sq2,
    const float* __restrict__ cv, float* __restrict__ out) {
    __shared__ alignas(16) uint8_t As[128 * 128];
    __shared__ alignas(16) uint8_t Bs[128 * 128];
    __shared__ float sqi1[128], sqj1[128], sqi2[128], sqj2[128];
    __shared__ float red[4];
    int tid = threadIdx.x;
    int ti = 0, r = blockIdx.x;
    while (r >= TT - ti) { r -= TT - ti; ++ti; }
    int tj = ti + r;
    int i0 = ti * 128, j0 = tj * 128;
    if (tid < 128) {
        sqi1[tid] = sq1[i0 + tid]; sqj1[tid] = sq1[j0 + tid];
        sqi2[tid] = sq2[i0 + tid]; sqj2[tid] = sq2[j0 + tid];
    }
    int lane = tid & 63, wv = tid >> 6;
    int wm = wv >> 1, wn = wv & 1, lm = lane & 15, quad = lane >> 4;
    f32x4 acc1[4][4] = {};
    f32x4 acc2[4][4] = {};
    gemm_loop_mx(t1f8 + (size_t)i0 * D1, t1f8 + (size_t)j0 * D1, D1, As, Bs, acc1, wv, lane, wm, wn, lm, quad);
    gemm_loop_mx(t2f8 + (size_t)i0 * D2, t2f8 + (size_t)j0 * D2, D2, As, Bs, acc2, wv, lane, wm, wn, lm, quad);
    float c1 = cv[0], c2 = cv[1];
    float local = 0.f;
    bool diag = (ti == tj);
#pragma unroll
    for (int mi = 0; mi < 4; ++mi) {
        int rbase = wm * 64 + mi * 16 + quad * 4;
#pragma unroll
        for (int ni = 0; ni < 4; ++ni) {
            int col = wn * 64 + ni * 16 + lm;
            float sb1 = sqj1[col], sb2 = sqj2[col];
#pragma unroll
            for (int rr = 0; rr < 4; ++rr) {
                int row = rbase + rr;
                float l2a = fmaxf(sqi1[row] + sb1 - 2.f * acc1[mi][ni][rr], 0.f);
                float l2b = fmaxf(sqi2[row] + sb2 - 2.f * acc2[mi][ni][rr], 0.f);
                float t1 = __builtin_amdgcn_exp2f(-l2a * c1);
                float k1 = t1; float u1 = t1 * t1; k1 += u1; u1 *= u1; k1 += u1; u1 *= u1; k1 += u1; u1 *= u1; k1 += u1;
                float t2 = __builtin_amdgcn_exp2f(-l2b * c2);
                float k2 = t2; float u2 = t2 * t2; k2 += u2; u2 *= u2; k2 += u2; u2 *= u2; k2 += u2; u2 *= u2; k2 += u2;
                float v = k1 * k2;
                if (diag && (row == col)) v = 0.f;
                local += v;
            }
        }
    }
    for (int o = 32; o; o >>= 1) local += __shfl_down(local, o);
    if (lane == 0) red[wv] = local;
    __syncthreads();
    if (tid == 0) {
        bool same = (i0 < BHALF) == (j0 < BHALF);
        float w = same ? (1.0f / ((float)BHALF * (float)(BHALF - 1)))
                       : (-1.0f / ((float)BHALF * (float)BHALF));
        if (!diag) w *= 2.f;
        atomicAdd(out, (red[0] + red[1] + red[2] + red[3]) * w);
    }
}

extern "C" void kernel_launch(void* const* d_in, const int* in_sizes, int n_in,
                              void* d_out, int out_size, void* d_ws, size_t ws_size,
                              hipStream_t stream) {
    const float* z1s = (const float*)d_in[0];
    const float* z1t = (const float*)d_in[1];
    const float* z2s = (const float*)d_in[2];
    const float* z2t = (const float*)d_in[3];
    float* out = (float*)d_out;

    float* ws = (float*)d_ws;
    float* sq1 = ws;              // 4096
    float* sq2 = ws + 4096;       // 4096
    float* s1  = ws + 8192;       // 4096
    float* s2  = ws + 12288;      // 2048
    float* acc = ws + 14336;      // [2]=c1 [3]=c2
    uint8_t* t1f8 = (uint8_t*)(ws + 14344);            // 16B-aligned
    uint8_t* t2f8 = t1f8 + (size_t)NTOT * D1;
    float* G1 = (float*)(t2f8 + (size_t)NTOT * D2);    // 16B-aligned (offsets mult of 16)
    float* G2 = G1 + (size_t)NTILES * 16384;
    size_t need_big = (size_t)14344 * 4
                    + ((size_t)NTOT * D1 + (size_t)NTOT * D2)
                    + (size_t)NTILES * 16384 * 2 * 4;

    prep_kernel<<<8192, 256, 0, stream>>>(z1s, z1t, z2s, z2t, sq1, sq2, t1f8, t2f8, s1, s2);
    colsum_fp8_kernel<<<48, 256, 0, stream>>>(t1f8, t2f8, s1, s2);
    finalize_kernel<<<1, 256, 0, stream>>>(s1, s2, sq1, sq2, acc, out);

    if (ws_size >= need_big) {
        gram_kernel<<<1056, 256, 0, stream>>>(t1f8, t2f8, G1, G2);
        epi_kernel<<<NTILES, 256, 0, stream>>>(G1, G2, sq1, sq2, acc + 2, out);
    } else {
        jmmd_fused<<<NTILES, 256, 0, stream>>>(t1f8, t2f8, sq1, sq2, acc + 2, out);
    }
}

// Round 6
// 302.822 us; speedup vs baseline: 1.5976x; 1.5976x over previous
//
#include <hip/hip_runtime.h>
#include <cstdint>

#define NTOT 4096   // 2b rows
#define BHALF 2048  // b
#define D1 4096
#define D2 2048
#define TT 32       // 4096/128 tiles per dim
#define NTILES 528  // TT*(TT+1)/2

typedef __attribute__((ext_vector_type(4))) float f32x4;
typedef __attribute__((ext_vector_type(8))) int i32x8;

// async 16B global->LDS DMA (wave-uniform LDS base + lane*16 scatter)
__device__ __forceinline__ void glds16(const uint8_t* g, uint8_t* l) {
    __builtin_amdgcn_global_load_lds(
        (const __attribute__((address_space(1))) void*)(uintptr_t)g,
        (__attribute__((address_space(3))) void*)(uint32_t)(uintptr_t)l,
        16, 0, 0);
}

// e4m3fn decode (for colsum only; data never near NaN/448)
__device__ __forceinline__ float fp8dec(unsigned b) {
    unsigned e = (b >> 3) & 15u, m = b & 7u;
    float v = e ? __uint_as_float(((e + 120u) << 23) | (m << 20))
                : (float)m * 0.001953125f;   // subnormal: m * 2^-9
    return (b & 128u) ? -v : v;
}

// ---------------- prep: per-row sumsq (fp32) + fp8 e4m3 convert ----------------
// blocks 0..4095: matrix1 rows; 4096..8191: matrix2 rows.
// blocks 0/1 additionally zero the colsum arrays (stream-ordered before colsum).
__global__ void prep_kernel(const float* __restrict__ z1s, const float* __restrict__ z1t,
                            const float* __restrict__ z2s, const float* __restrict__ z2t,
                            float* __restrict__ sq1, float* __restrict__ sq2,
                            uint8_t* __restrict__ t1f8, uint8_t* __restrict__ t2f8,
                            float* __restrict__ s1, float* __restrict__ s2) {
    int bid = blockIdx.x;
    int tid = threadIdx.x;
    if (bid == 0) { for (int i = tid; i < 4096; i += 256) s1[i] = 0.f; }
    if (bid == 1) { for (int i = tid; i < 2048; i += 256) s2[i] = 0.f; }
    int which = bid >> 12;
    int row = bid & 4095;
    int d = which ? D2 : D1;
    const float* s_ = which ? z2s : z1s;
    const float* t_ = which ? z2t : z1t;
    const float* src = (row < BHALF) ? s_ + (size_t)row * d : t_ + (size_t)(row - BHALF) * d;
    uint8_t* dst = (which ? t2f8 : t1f8) + (size_t)row * d;
    float* sq = which ? sq2 : sq1;
    const float4* src4 = (const float4*)src;
    float a = 0.f;
    int n8 = d >> 3;
    for (int i = tid; i < n8; i += 256) {
        float4 v0 = src4[2 * i], v1 = src4[2 * i + 1];
        a += v0.x * v0.x + v0.y * v0.y + v0.z * v0.z + v0.w * v0.w;
        a += v1.x * v1.x + v1.y * v1.y + v1.z * v1.z + v1.w * v1.w;
        int w0 = __builtin_amdgcn_cvt_pk_fp8_f32(v0.x, v0.y, 0, 0);
        w0 = __builtin_amdgcn_cvt_pk_fp8_f32(v0.z, v0.w, w0, 1);
        int w1 = __builtin_amdgcn_cvt_pk_fp8_f32(v1.x, v1.y, 0, 0);
        w1 = __builtin_amdgcn_cvt_pk_fp8_f32(v1.z, v1.w, w1, 1);
        ((uint2*)dst)[i] = uint2{(unsigned)w0, (unsigned)w1};
    }
    for (int o = 32; o; o >>= 1) a += __shfl_down(a, o);
    __shared__ float sh[4];
    int lane = tid & 63, w = tid >> 6;
    if (lane == 0) sh[w] = a;
    __syncthreads();
    if (tid == 0) sq[row] = sh[0] + sh[1] + sh[2] + sh[3];
}

// ---------------- column sums from fp8 copies (bandwidth term only) ----------------
// 64-row panels for parallelism (R5 post-mortem: 48-block version was
// latency-serialized at 2% occupancy, 220 us).
// blocks 0..255: matrix1 (4 colchunks x 64 row panels); 256..383: matrix2 (2 x 64)
__global__ void colsum_fp8_kernel(const uint8_t* __restrict__ t1f8,
                                  const uint8_t* __restrict__ t2f8,
                                  float* __restrict__ s1, float* __restrict__ s2) {
    int bid = blockIdx.x;
    int which = bid >= 256;
    int local = which ? bid - 256 : bid;
    int d = which ? D2 : D1;
    int colchunks = d >> 10;
    int cb = local % colchunks, rb = local / colchunks;
    const uint8_t* base = which ? t2f8 : t1f8;
    float* s = which ? s2 : s1;
    int col = (cb << 10) + threadIdx.x * 4;
    int r0 = rb * 64;
    float a0 = 0.f, a1 = 0.f, a2 = 0.f, a3 = 0.f;
    const uint8_t* p = base + (size_t)r0 * d + col;
#pragma unroll 4
    for (int r = 0; r < 64; ++r) {
        uchar4 u = *(const uchar4*)(p + (size_t)r * d);
        a0 += fp8dec(u.x); a1 += fp8dec(u.y); a2 += fp8dec(u.z); a3 += fp8dec(u.w);
    }
    atomicAdd(&s[col], a0); atomicAdd(&s[col + 1], a1);
    atomicAdd(&s[col + 2], a2); atomicAdd(&s[col + 3], a3);
}

// ---------------- finalize: bandwidth constants + loss bias ----------------
__global__ void finalize_kernel(const float* __restrict__ s1, const float* __restrict__ s2,
                                const float* __restrict__ sq1, const float* __restrict__ sq2,
                                float* __restrict__ acc, float* __restrict__ out) {
    int tid = threadIdx.x;
    float a1 = 0.f, a2 = 0.f, q1 = 0.f, q2 = 0.f;
    for (int i = tid; i < 4096; i += 256) { float v = s1[i]; a1 += v * v; q1 += sq1[i]; q2 += sq2[i]; }
    for (int i = tid; i < 2048; i += 256) { float v = s2[i]; a2 += v * v; }
    for (int o = 32; o; o >>= 1) {
        a1 += __shfl_down(a1, o); a2 += __shfl_down(a2, o);
        q1 += __shfl_down(q1, o); q2 += __shfl_down(q2, o);
    }
    __shared__ float sh[4][4];
    int lane = tid & 63, w = tid >> 6;
    if (lane == 0) { sh[0][w] = a1; sh[1][w] = a2; sh[2][w] = q1; sh[3][w] = q2; }
    __syncthreads();
    if (tid == 0) {
        double ss1 = (double)sh[0][0] + sh[0][1] + sh[0][2] + sh[0][3];
        double ss2 = (double)sh[1][0] + sh[1][1] + sh[1][2] + sh[1][3];
        double t1 = (double)sh[2][0] + sh[2][1] + sh[2][2] + sh[2][3];
        double t2 = (double)sh[3][0] + sh[3][1] + sh[3][2] + sh[3][3];
        double S1 = 2.0 * (double)NTOT * t1 - 2.0 * ss1;
        double S2 = 2.0 * (double)NTOT * t2 - 2.0 * ss2;
        const double L2E = 1.4426950408889634;
        double nn = (double)NTOT * (double)(NTOT - 1);
        acc[2] = (float)(nn * L2E / (4.0 * S1));
        acc[3] = (float)(nn * L2E / (4.0 * S2));
        out[0] = 2.0f / (float)(BHALF - 1);
    }
}

// ---------------- MX-fp8 GEMM loop: BK=128 bytes, 16x16x128 scaled MFMA ----------
// LDS: row-major [128 rows][128 B]. lane L stages row (L>>3), 16B chunk (L&7)
// => per-8-lane groups cover contiguous 128B global segments (coalesced DMA).
// Fragment: lane holds 32 consecutive k-bytes at k-offset quad*32 (one MX block
// of 32 => uniform scale 0x7F = 1.0 is exact).
__device__ __forceinline__ void gemm_loop_mx(const uint8_t* __restrict__ ga,
                                             const uint8_t* __restrict__ gb,
                                             int d, uint8_t* As, uint8_t* Bs,
                                             f32x4 (&acc)[4][4], int wv, int lane,
                                             int wm, int wn, int lm, int quad) {
    int rsub = lane >> 3;              // 0..7
    int ch = lane & 7;                 // 16B chunk within the 128B row-slab
    const uint8_t* gaL = ga + (size_t)(wv * 32 + rsub) * d + ch * 16;
    const uint8_t* gbL = gb + (size_t)(wv * 32 + rsub) * d + ch * 16;
    uint8_t* AsW = As + wv * 32 * 128;
    uint8_t* BsW = Bs + wv * 32 * 128;
    for (int k0 = 0; k0 < d; k0 += 128) {
        __syncthreads();
#pragma unroll
        for (int i = 0; i < 4; ++i) {
            glds16(gaL + ((size_t)i * 8 * d + k0), AsW + i * 8 * 128);
            glds16(gbL + ((size_t)i * 8 * d + k0), BsW + i * 8 * 128);
        }
        __syncthreads();
        union F { uint4 h[2]; i32x8 v; };
        F a[4];
#pragma unroll
        for (int mi = 0; mi < 4; ++mi) {
            const uint4* p = (const uint4*)&As[(wm * 64 + mi * 16 + lm) * 128 + quad * 32];
            a[mi].h[0] = p[0]; a[mi].h[1] = p[1];
        }
#pragma unroll
        for (int ni = 0; ni < 4; ++ni) {
            F b;
            const uint4* p = (const uint4*)&Bs[(wn * 64 + ni * 16 + lm) * 128 + quad * 32];
            b.h[0] = p[0]; b.h[1] = p[1];
#pragma unroll
            for (int mi = 0; mi < 4; ++mi)
                acc[mi][ni] = __builtin_amdgcn_mfma_scale_f32_16x16x128_f8f6f4(
                    a[mi].v, b.v, acc[mi][ni], 0, 0, 0, 0x7F7F7F7F, 0, 0x7F7F7F7F);
        }
    }
}

// ---------------- Gram kernel: 1056 blocks = 528 tiles x {GEMM1, GEMM2} ----------
// Compact supertile->XCD map (round-robin blockIdx%8 -> XCD): 6 off-diag 8x8
// supertile regions -> XCD 0..5, 2 diagonal pairs -> XCD 6..7.
__global__ __launch_bounds__(256, 4) void gram_kernel(
    const uint8_t* __restrict__ t1f8, const uint8_t* __restrict__ t2f8,
    float* __restrict__ G1, float* __restrict__ G2) {
    __shared__ alignas(16) uint8_t As[128 * 128];
    __shared__ alignas(16) uint8_t Bs[128 * 128];
    int lid = blockIdx.x;
    int lin = (lid & 7) * 132 + (lid >> 3);
    int ti, tj, which;
    if (lin < 768) {
        int r = lin >> 7, q = lin & 127;
        which = q & 1;
        int t = q >> 1, a = t >> 3, b = t & 7;
        const int si_t[6] = {0, 0, 0, 1, 1, 2};
        const int sj_t[6] = {1, 2, 3, 2, 3, 3};
        ti = si_t[r] * 8 + a; tj = sj_t[r] * 8 + b;
    } else {
        int m = lin - 768;
        int dd = m / 144, q = m % 144;
        which = q & 1;
        int t = q >> 1;
        int s = 2 * dd + (t >= 36 ? 1 : 0);
        int tl = t >= 36 ? t - 36 : t;
        int a = 0;
        while (tl >= 8 - a) { tl -= 8 - a; ++a; }
        ti = s * 8 + a; tj = s * 8 + a + tl;
    }
    int tcan = TT * ti - (ti * (ti - 1)) / 2 + (tj - ti);
    int i0 = ti * 128, j0 = tj * 128;
    int d = which ? D2 : D1;
    const uint8_t* base = which ? t2f8 : t1f8;
    float* G = (which ? G2 : G1) + (size_t)tcan * 16384;

    int tid = threadIdx.x, lane = tid & 63, wv = tid >> 6;
    int wm = wv >> 1, wn = wv & 1, lm = lane & 15, quad = lane >> 4;
    f32x4 acc[4][4] = {};
    gemm_loop_mx(base + (size_t)i0 * d, base + (size_t)j0 * d, d, As, Bs, acc,
                 wv, lane, wm, wn, lm, quad);
#pragma unroll
    for (int mi = 0; mi < 4; ++mi)
#pragma unroll
        for (int ni = 0; ni < 4; ++ni)
#pragma unroll
            for (int rr = 0; rr < 4; ++rr)
                G[(size_t)(wm * 64 + mi * 16 + quad * 4 + rr) * 128 + wn * 64 + ni * 16 + lm] =
                    acc[mi][ni][rr];
}

// ---------------- epilogue: read Grams, 5-kernel sum, product, weighted reduce ----
__global__ __launch_bounds__(256, 4) void epi_kernel(
    const float* __restrict__ G1, const float* __restrict__ G2,
    const float* __restrict__ sq1, const float* __restrict__ sq2,
    const float* __restrict__ cv, float* __restrict__ out) {
    __shared__ float sqi1[128], sqj1[128], sqi2[128], sqj2[128];
    __shared__ float red[4];
    int t = blockIdx.x;
    int ti = 0, r = t;
    while (r >= TT - ti) { r -= TT - ti; ++ti; }
    int tj = ti + r;
    int i0 = ti * 128, j0 = tj * 128;
    int tid = threadIdx.x;
    if (tid < 128) {
        sqi1[tid] = sq1[i0 + tid]; sqj1[tid] = sq1[j0 + tid];
        sqi2[tid] = sq2[i0 + tid]; sqj2[tid] = sq2[j0 + tid];
    }
    __syncthreads();
    float c1 = cv[0], c2 = cv[1];
    const float4* g1 = (const float4*)(G1 + (size_t)t * 16384);
    const float4* g2 = (const float4*)(G2 + (size_t)t * 16384);
    bool diag = (ti == tj);
    float local = 0.f;
#pragma unroll 4
    for (int it = 0; it < 16; ++it) {
        int e4 = it * 256 + tid;
        int row = e4 >> 5, col = (e4 & 31) * 4;
        float4 a = g1[e4], b = g2[e4];
        float si1 = sqi1[row], si2 = sqi2[row];
        float ax[4] = {a.x, a.y, a.z, a.w}, bx[4] = {b.x, b.y, b.z, b.w};
#pragma unroll
        for (int j = 0; j < 4; ++j) {
            float l2a = fmaxf(si1 + sqj1[col + j] - 2.f * ax[j], 0.f);
            float l2b = fmaxf(si2 + sqj2[col + j] - 2.f * bx[j], 0.f);
            float t1 = __builtin_amdgcn_exp2f(-l2a * c1);
            float k1 = t1; float u1 = t1 * t1; k1 += u1; u1 *= u1; k1 += u1; u1 *= u1; k1 += u1; u1 *= u1; k1 += u1;
            float t2 = __builtin_amdgcn_exp2f(-l2b * c2);
            float k2 = t2; float u2 = t2 * t2; k2 += u2; u2 *= u2; k2 += u2; u2 *= u2; k2 += u2; u2 *= u2; k2 += u2;
            float v = k1 * k2;
            if (diag && (row == col + j)) v = 0.f;
            local += v;
        }
    }
    for (int o = 32; o; o >>= 1) local += __shfl_down(local, o);
    int lane = tid & 63, wv = tid >> 6;
    if (lane == 0) red[wv] = local;
    __syncthreads();
    if (tid == 0) {
        bool same = (i0 < BHALF) == (j0 < BHALF);
        float w = same ? (1.0f / ((float)BHALF * (float)(BHALF - 1)))
                       : (-1.0f / ((float)BHALF * (float)BHALF));
        if (!diag) w *= 2.f;
        atomicAdd(out, (red[0] + red[1] + red[2] + red[3]) * w);
    }
}

// ---------------- fallback: fused dual-GEMM (ws too small for Gram buffers) ------
__global__ __launch_bounds__(256, 2) void jmmd_fused(
    const uint8_t* __restrict__ t1f8, const uint8_t* __restrict__ t2f8,
    const float* __restrict__ sq1, const float* __restrict__ sq2,
    const float* __restrict__ cv, float* __restrict__ out) {
    __shared__ alignas(16) uint8_t As[128 * 128];
    __shared__ alignas(16) uint8_t Bs[128 * 128];
    __shared__ float sqi1[128], sqj1[128], sqi2[128], sqj2[128];
    __shared__ float red[4];
    int tid = threadIdx.x;
    int ti = 0, r = blockIdx.x;
    while (r >= TT - ti) { r -= TT - ti; ++ti; }
    int tj = ti + r;
    int i0 = ti * 128, j0 = tj * 128;
    if (tid < 128) {
        sqi1[tid] = sq1[i0 + tid]; sqj1[tid] = sq1[j0 + tid];
        sqi2[tid] = sq2[i0 + tid]; sqj2[tid] = sq2[j0 + tid];
    }
    int lane = tid & 63, wv = tid >> 6;
    int wm = wv >> 1, wn = wv & 1, lm = lane & 15, quad = lane >> 4;
    f32x4 acc1[4][4] = {};
    f32x4 acc2[4][4] = {};
    gemm_loop_mx(t1f8 + (size_t)i0 * D1, t1f8 + (size_t)j0 * D1, D1, As, Bs, acc1, wv, lane, wm, wn, lm, quad);
    gemm_loop_mx(t2f8 + (size_t)i0 * D2, t2f8 + (size_t)j0 * D2, D2, As, Bs, acc2, wv, lane, wm, wn, lm, quad);
    float c1 = cv[0], c2 = cv[1];
    float local = 0.f;
    bool diag = (ti == tj);
#pragma unroll
    for (int mi = 0; mi < 4; ++mi) {
        int rbase = wm * 64 + mi * 16 + quad * 4;
#pragma unroll
        for (int ni = 0; ni < 4; ++ni) {
            int col = wn * 64 + ni * 16 + lm;
            float sb1 = sqj1[col], sb2 = sqj2[col];
#pragma unroll
            for (int rr = 0; rr < 4; ++rr) {
                int row = rbase + rr;
                float l2a = fmaxf(sqi1[row] + sb1 - 2.f * acc1[mi][ni][rr], 0.f);
                float l2b = fmaxf(sqi2[row] + sb2 - 2.f * acc2[mi][ni][rr], 0.f);
                float t1 = __builtin_amdgcn_exp2f(-l2a * c1);
                float k1 = t1; float u1 = t1 * t1; k1 += u1; u1 *= u1; k1 += u1; u1 *= u1; k1 += u1; u1 *= u1; k1 += u1;
                float t2 = __builtin_amdgcn_exp2f(-l2b * c2);
                float k2 = t2; float u2 = t2 * t2; k2 += u2; u2 *= u2; k2 += u2; u2 *= u2; k2 += u2; u2 *= u2; k2 += u2;
                float v = k1 * k2;
                if (diag && (row == col)) v = 0.f;
                local += v;
            }
        }
    }
    for (int o = 32; o; o >>= 1) local += __shfl_down(local, o);
    if (lane == 0) red[wv] = local;
    __syncthreads();
    if (tid == 0) {
        bool same = (i0 < BHALF) == (j0 < BHALF);
        float w = same ? (1.0f / ((float)BHALF * (float)(BHALF - 1)))
                       : (-1.0f / ((float)BHALF * (float)BHALF));
        if (!diag) w *= 2.f;
        atomicAdd(out, (red[0] + red[1] + red[2] + red[3]) * w);
    }
}

extern "C" void kernel_launch(void* const* d_in, const int* in_sizes, int n_in,
                              void* d_out, int out_size, void* d_ws, size_t ws_size,
                              hipStream_t stream) {
    const float* z1s = (const float*)d_in[0];
    const float* z1t = (const float*)d_in[1];
    const float* z2s = (const float*)d_in[2];
    const float* z2t = (const float*)d_in[3];
    float* out = (float*)d_out;

    float* ws = (float*)d_ws;
    float* sq1 = ws;              // 4096
    float* sq2 = ws + 4096;       // 4096
    float* s1  = ws + 8192;       // 4096
    float* s2  = ws + 12288;      // 2048
    float* acc = ws + 14336;      // [2]=c1 [3]=c2
    uint8_t* t1f8 = (uint8_t*)(ws + 14344);            // 16B-aligned
    uint8_t* t2f8 = t1f8 + (size_t)NTOT * D1;
    float* G1 = (float*)(t2f8 + (size_t)NTOT * D2);    // 16B-aligned (offsets mult of 16)
    float* G2 = G1 + (size_t)NTILES * 16384;
    size_t need_big = (size_t)14344 * 4
                    + ((size_t)NTOT * D1 + (size_t)NTOT * D2)
                    + (size_t)NTILES * 16384 * 2 * 4;

    prep_kernel<<<8192, 256, 0, stream>>>(z1s, z1t, z2s, z2t, sq1, sq2, t1f8, t2f8, s1, s2);
    colsum_fp8_kernel<<<384, 256, 0, stream>>>(t1f8, t2f8, s1, s2);
    finalize_kernel<<<1, 256, 0, stream>>>(s1, s2, sq1, sq2, acc, out);

    if (ws_size >= need_big) {
        gram_kernel<<<1056, 256, 0, stream>>>(t1f8, t2f8, G1, G2);
        epi_kernel<<<NTILES, 256, 0, stream>>>(G1, G2, sq1, sq2, acc + 2, out);
    } else {
        jmmd_fused<<<NTILES, 256, 0, stream>>>(t1f8, t2f8, sq1, sq2, acc + 2, out);
    }
}

// Round 7
// 294.381 us; speedup vs baseline: 1.6434x; 1.0287x over previous
//
#include <hip/hip_runtime.h>
#include <cstdint>

#define NTOT 4096   // 2b rows
#define BHALF 2048  // b
#define D1 4096
#define D2 2048
#define TT 32       // 4096/128 tiles per dim
#define NTILES 528  // TT*(TT+1)/2

typedef __attribute__((ext_vector_type(4))) float f32x4;
typedef __attribute__((ext_vector_type(4))) int i32x4;
typedef __attribute__((ext_vector_type(8))) int i32x8;

// async 16B global->LDS DMA (wave-uniform LDS base + lane*16 scatter)
__device__ __forceinline__ void glds16(const uint8_t* g, uint8_t* l) {
    __builtin_amdgcn_global_load_lds(
        (const __attribute__((address_space(1))) void*)(uintptr_t)g,
        (__attribute__((address_space(3))) void*)(uint32_t)(uintptr_t)l,
        16, 0, 0);
}

// raw LDS b128 read, opaque to the compiler's waitcnt insertion
__device__ __forceinline__ i32x4 ldsr(uint32_t addr) {
    i32x4 r;
    asm volatile("ds_read_b128 %0, %1" : "=v"(r) : "v"(addr));
    return r;
}

// e4m3fn decode (for colsum only; data never near NaN/448)
__device__ __forceinline__ float fp8dec(unsigned b) {
    unsigned e = (b >> 3) & 15u, m = b & 7u;
    float v = e ? __uint_as_float(((e + 120u) << 23) | (m << 20))
                : (float)m * 0.001953125f;   // subnormal: m * 2^-9
    return (b & 128u) ? -v : v;
}

// ---------------- prep: per-row sumsq (fp32) + fp8 e4m3 convert ----------------
__global__ void prep_kernel(const float* __restrict__ z1s, const float* __restrict__ z1t,
                            const float* __restrict__ z2s, const float* __restrict__ z2t,
                            float* __restrict__ sq1, float* __restrict__ sq2,
                            uint8_t* __restrict__ t1f8, uint8_t* __restrict__ t2f8,
                            float* __restrict__ s1, float* __restrict__ s2) {
    int bid = blockIdx.x;
    int tid = threadIdx.x;
    if (bid == 0) { for (int i = tid; i < 4096; i += 256) s1[i] = 0.f; }
    if (bid == 1) { for (int i = tid; i < 2048; i += 256) s2[i] = 0.f; }
    int which = bid >> 12;
    int row = bid & 4095;
    int d = which ? D2 : D1;
    const float* s_ = which ? z2s : z1s;
    const float* t_ = which ? z2t : z1t;
    const float* src = (row < BHALF) ? s_ + (size_t)row * d : t_ + (size_t)(row - BHALF) * d;
    uint8_t* dst = (which ? t2f8 : t1f8) + (size_t)row * d;
    float* sq = which ? sq2 : sq1;
    const float4* src4 = (const float4*)src;
    float a = 0.f;
    int n8 = d >> 3;
    for (int i = tid; i < n8; i += 256) {
        float4 v0 = src4[2 * i], v1 = src4[2 * i + 1];
        a += v0.x * v0.x + v0.y * v0.y + v0.z * v0.z + v0.w * v0.w;
        a += v1.x * v1.x + v1.y * v1.y + v1.z * v1.z + v1.w * v1.w;
        int w0 = __builtin_amdgcn_cvt_pk_fp8_f32(v0.x, v0.y, 0, 0);
        w0 = __builtin_amdgcn_cvt_pk_fp8_f32(v0.z, v0.w, w0, 1);
        int w1 = __builtin_amdgcn_cvt_pk_fp8_f32(v1.x, v1.y, 0, 0);
        w1 = __builtin_amdgcn_cvt_pk_fp8_f32(v1.z, v1.w, w1, 1);
        ((uint2*)dst)[i] = uint2{(unsigned)w0, (unsigned)w1};
    }
    for (int o = 32; o; o >>= 1) a += __shfl_down(a, o);
    __shared__ float sh[4];
    int lane = tid & 63, w = tid >> 6;
    if (lane == 0) sh[w] = a;
    __syncthreads();
    if (tid == 0) sq[row] = sh[0] + sh[1] + sh[2] + sh[3];
}

// ---------------- column sums from fp8 copies (bandwidth term only) ----------------
__global__ void colsum_fp8_kernel(const uint8_t* __restrict__ t1f8,
                                  const uint8_t* __restrict__ t2f8,
                                  float* __restrict__ s1, float* __restrict__ s2) {
    int bid = blockIdx.x;
    int which = bid >= 256;
    int local = which ? bid - 256 : bid;
    int d = which ? D2 : D1;
    int colchunks = d >> 10;
    int cb = local % colchunks, rb = local / colchunks;
    const uint8_t* base = which ? t2f8 : t1f8;
    float* s = which ? s2 : s1;
    int col = (cb << 10) + threadIdx.x * 4;
    int r0 = rb * 64;
    float a0 = 0.f, a1 = 0.f, a2 = 0.f, a3 = 0.f;
    const uint8_t* p = base + (size_t)r0 * d + col;
#pragma unroll 4
    for (int r = 0; r < 64; ++r) {
        uchar4 u = *(const uchar4*)(p + (size_t)r * d);
        a0 += fp8dec(u.x); a1 += fp8dec(u.y); a2 += fp8dec(u.z); a3 += fp8dec(u.w);
    }
    atomicAdd(&s[col], a0); atomicAdd(&s[col + 1], a1);
    atomicAdd(&s[col + 2], a2); atomicAdd(&s[col + 3], a3);
}

// ---------------- finalize: bandwidth constants + loss bias ----------------
__global__ void finalize_kernel(const float* __restrict__ s1, const float* __restrict__ s2,
                                const float* __restrict__ sq1, const float* __restrict__ sq2,
                                float* __restrict__ acc, float* __restrict__ out) {
    int tid = threadIdx.x;
    float a1 = 0.f, a2 = 0.f, q1 = 0.f, q2 = 0.f;
    for (int i = tid; i < 4096; i += 256) { float v = s1[i]; a1 += v * v; q1 += sq1[i]; q2 += sq2[i]; }
    for (int i = tid; i < 2048; i += 256) { float v = s2[i]; a2 += v * v; }
    for (int o = 32; o; o >>= 1) {
        a1 += __shfl_down(a1, o); a2 += __shfl_down(a2, o);
        q1 += __shfl_down(q1, o); q2 += __shfl_down(q2, o);
    }
    __shared__ float sh[4][4];
    int lane = tid & 63, w = tid >> 6;
    if (lane == 0) { sh[0][w] = a1; sh[1][w] = a2; sh[2][w] = q1; sh[3][w] = q2; }
    __syncthreads();
    if (tid == 0) {
        double ss1 = (double)sh[0][0] + sh[0][1] + sh[0][2] + sh[0][3];
        double ss2 = (double)sh[1][0] + sh[1][1] + sh[1][2] + sh[1][3];
        double t1 = (double)sh[2][0] + sh[2][1] + sh[2][2] + sh[2][3];
        double t2 = (double)sh[3][0] + sh[3][1] + sh[3][2] + sh[3][3];
        double S1 = 2.0 * (double)NTOT * t1 - 2.0 * ss1;
        double S2 = 2.0 * (double)NTOT * t2 - 2.0 * ss2;
        const double L2E = 1.4426950408889634;
        double nn = (double)NTOT * (double)(NTOT - 1);
        acc[2] = (float)(nn * L2E / (4.0 * S1));
        acc[3] = (float)(nn * L2E / (4.0 * S2));
        out[0] = 2.0f / (float)(BHALF - 1);
    }
}

// ---------------- pipelined MX-fp8 GEMM K-loop ----------------
// Double-buffered LDS; prefetch issued BEFORE the barrier; raw s_barrier with
// manual s_waitcnt vmcnt(8) (prefetch stays in flight across the barrier —
// AITER pattern). Frag reads via opaque asm ds_read_b128 + manual lgkmcnt(0)
// tied to the fragment registers. Second barrier (non-draining) covers the WAR
// on the buffer being refilled next iteration.
// LDS per buffer: A[128][128B] + B[128][128B]; XOR chunk swizzle:
// logical 16B chunk c of row r lives at slot c^(r&7)  (conflict-free reads,
// coalesced DMA within each 8-lane/128B group — validated R2: 0 conflicts).
__device__ __forceinline__ void gemm_mx_pipe(const uint8_t* __restrict__ ga,
                                             const uint8_t* __restrict__ gb,
                                             int d,
                                             uint8_t* A0, uint8_t* B0,
                                             uint8_t* A1, uint8_t* B1,
                                             f32x4 (&acc)[4][4], int wv, int lane,
                                             int wm, int wn, int lm, int quad) {
    int nsteps = d >> 7;
    int rsub = lane >> 3;
    int ql = (lane & 7) ^ rsub;          // swizzled source chunk
    const uint8_t* pa = ga + (size_t)(wv * 32 + rsub) * d + ql * 16;
    const uint8_t* pb = gb + (size_t)(wv * 32 + rsub) * d + ql * 16;
    uint8_t* dA[2] = { A0 + wv * 4096, A1 + wv * 4096 };
    uint8_t* dB[2] = { B0 + wv * 4096, B1 + wv * 4096 };
    uint32_t baseA[2] = { (uint32_t)(uintptr_t)A0, (uint32_t)(uintptr_t)A1 };
    uint32_t baseB[2] = { (uint32_t)(uintptr_t)B0, (uint32_t)(uintptr_t)B1 };
    int s0 = ((2 * quad) ^ (lm & 7)) * 16;
    int s1 = ((2 * quad + 1) ^ (lm & 7)) * 16;
    uint32_t offA[4], offB[4];
#pragma unroll
    for (int i = 0; i < 4; ++i) {
        offA[i] = (uint32_t)((wm * 64 + i * 16 + lm) * 128);
        offB[i] = (uint32_t)((wn * 64 + i * 16 + lm) * 128);
    }
    // prime buffer 0 (k=0)
#pragma unroll
    for (int i = 0; i < 4; ++i) {
        glds16(pa + (size_t)i * 8 * d, dA[0] + i * 1024);
        glds16(pb + (size_t)i * 8 * d, dB[0] + i * 1024);
    }
    for (int k = 0; k < nsteps; ++k) {
        int cur = k & 1, nxt = cur ^ 1;
        // prefetch k+1 (dummy re-fetch of k=0 on the last iter keeps vmcnt uniform;
        // it targets the not-being-read buffer -> harmless)
        size_t koff = (size_t)((k + 1 < nsteps) ? (k + 1) : 0) << 7;
#pragma unroll
        for (int i = 0; i < 4; ++i) {
            glds16(pa + koff + (size_t)i * 8 * d, dA[nxt] + i * 1024);
            glds16(pb + koff + (size_t)i * 8 * d, dB[nxt] + i * 1024);
        }
        // own prev 8 loads (buffer cur) done; 8 prefetch loads stay in flight
        asm volatile("s_waitcnt vmcnt(8)\n\ts_barrier" ::: "memory");
        i32x4 a00, a01, a10, a11, a20, a21, a30, a31;
        i32x4 b00, b01, b10, b11, b20, b21, b30, b31;
        a00 = ldsr(baseA[cur] + offA[0] + s0); a01 = ldsr(baseA[cur] + offA[0] + s1);
        a10 = ldsr(baseA[cur] + offA[1] + s0); a11 = ldsr(baseA[cur] + offA[1] + s1);
        a20 = ldsr(baseA[cur] + offA[2] + s0); a21 = ldsr(baseA[cur] + offA[2] + s1);
        a30 = ldsr(baseA[cur] + offA[3] + s0); a31 = ldsr(baseA[cur] + offA[3] + s1);
        b00 = ldsr(baseB[cur] + offB[0] + s0); b01 = ldsr(baseB[cur] + offB[0] + s1);
        b10 = ldsr(baseB[cur] + offB[1] + s0); b11 = ldsr(baseB[cur] + offB[1] + s1);
        b20 = ldsr(baseB[cur] + offB[2] + s0); b21 = ldsr(baseB[cur] + offB[2] + s1);
        b30 = ldsr(baseB[cur] + offB[3] + s0); b31 = ldsr(baseB[cur] + offB[3] + s1);
        asm volatile("s_waitcnt lgkmcnt(0)"
                     : "+v"(a00), "+v"(a01), "+v"(a10), "+v"(a11),
                       "+v"(a20), "+v"(a21), "+v"(a30), "+v"(a31),
                       "+v"(b00), "+v"(b01), "+v"(b10), "+v"(b11),
                       "+v"(b20), "+v"(b21), "+v"(b30), "+v"(b31));
        union F { i32x4 h[2]; i32x8 v; };
        F ua[4], ub[4];
        ua[0].h[0] = a00; ua[0].h[1] = a01; ua[1].h[0] = a10; ua[1].h[1] = a11;
        ua[2].h[0] = a20; ua[2].h[1] = a21; ua[3].h[0] = a30; ua[3].h[1] = a31;
        ub[0].h[0] = b00; ub[0].h[1] = b01; ub[1].h[0] = b10; ub[1].h[1] = b11;
        ub[2].h[0] = b20; ub[2].h[1] = b21; ub[3].h[0] = b30; ub[3].h[1] = b31;
#pragma unroll
        for (int ni = 0; ni < 4; ++ni)
#pragma unroll
            for (int mi = 0; mi < 4; ++mi)
                acc[mi][ni] = __builtin_amdgcn_mfma_scale_f32_16x16x128_f8f6f4(
                    ua[mi].v, ub[ni].v, acc[mi][ni], 0, 0, 0, 0x7F7F7F7F, 0, 0x7F7F7F7F);
        // WAR guard: all waves' reads of buffer cur are complete (lgkmcnt(0)
        // above) before anyone's next-iteration DMA may target it
        asm volatile("s_barrier" ::: "memory");
    }
}

// ---------------- Gram kernel: 1056 blocks = 528 tiles x {GEMM1, GEMM2} ----------
__global__ __launch_bounds__(256, 2) void gram_kernel(
    const uint8_t* __restrict__ t1f8, const uint8_t* __restrict__ t2f8,
    float* __restrict__ G1, float* __restrict__ G2) {
    __shared__ alignas(16) uint8_t smem[4][16384];   // A0,B0,A1,B1
    int lid = blockIdx.x;
    int lin = (lid & 7) * 132 + (lid >> 3);
    int ti, tj, which;
    if (lin < 768) {
        int r = lin >> 7, q = lin & 127;
        which = q & 1;
        int t = q >> 1, a = t >> 3, b = t & 7;
        const int si_t[6] = {0, 0, 0, 1, 1, 2};
        const int sj_t[6] = {1, 2, 3, 2, 3, 3};
        ti = si_t[r] * 8 + a; tj = sj_t[r] * 8 + b;
    } else {
        int m = lin - 768;
        int dd = m / 144, q = m % 144;
        which = q & 1;
        int t = q >> 1;
        int s = 2 * dd + (t >= 36 ? 1 : 0);
        int tl = t >= 36 ? t - 36 : t;
        int a = 0;
        while (tl >= 8 - a) { tl -= 8 - a; ++a; }
        ti = s * 8 + a; tj = s * 8 + a + tl;
    }
    int tcan = TT * ti - (ti * (ti - 1)) / 2 + (tj - ti);
    int i0 = ti * 128, j0 = tj * 128;
    int d = which ? D2 : D1;
    const uint8_t* base = which ? t2f8 : t1f8;
    float* G = (which ? G2 : G1) + (size_t)tcan * 16384;

    int tid = threadIdx.x, lane = tid & 63, wv = tid >> 6;
    int wm = wv >> 1, wn = wv & 1, lm = lane & 15, quad = lane >> 4;
    f32x4 acc[4][4] = {};
    gemm_mx_pipe(base + (size_t)i0 * d, base + (size_t)j0 * d, d,
                 smem[0], smem[1], smem[2], smem[3],
                 acc, wv, lane, wm, wn, lm, quad);
#pragma unroll
    for (int mi = 0; mi < 4; ++mi)
#pragma unroll
        for (int ni = 0; ni < 4; ++ni)
#pragma unroll
            for (int rr = 0; rr < 4; ++rr)
                G[(size_t)(wm * 64 + mi * 16 + quad * 4 + rr) * 128 + wn * 64 + ni * 16 + lm] =
                    acc[mi][ni][rr];
}

// ---------------- epilogue: read Grams, 5-kernel sum, product, weighted reduce ----
__global__ __launch_bounds__(256, 4) void epi_kernel(
    const float* __restrict__ G1, const float* __restrict__ G2,
    const float* __restrict__ sq1, const float* __restrict__ sq2,
    const float* __restrict__ cv, float* __restrict__ out) {
    __shared__ float sqi1[128], sqj1[128], sqi2[128], sqj2[128];
    __shared__ float red[4];
    int t = blockIdx.x;
    int ti = 0, r = t;
    while (r >= TT - ti) { r -= TT - ti; ++ti; }
    int tj = ti + r;
    int i0 = ti * 128, j0 = tj * 128;
    int tid = threadIdx.x;
    if (tid < 128) {
        sqi1[tid] = sq1[i0 + tid]; sqj1[tid] = sq1[j0 + tid];
        sqi2[tid] = sq2[i0 + tid]; sqj2[tid] = sq2[j0 + tid];
    }
    __syncthreads();
    float c1 = cv[0], c2 = cv[1];
    const float4* g1 = (const float4*)(G1 + (size_t)t * 16384);
    const float4* g2 = (const float4*)(G2 + (size_t)t * 16384);
    bool diag = (ti == tj);
    float local = 0.f;
#pragma unroll 4
    for (int it = 0; it < 16; ++it) {
        int e4 = it * 256 + tid;
        int row = e4 >> 5, col = (e4 & 31) * 4;
        float4 a = g1[e4], b = g2[e4];
        float si1 = sqi1[row], si2 = sqi2[row];
        float ax[4] = {a.x, a.y, a.z, a.w}, bx[4] = {b.x, b.y, b.z, b.w};
#pragma unroll
        for (int j = 0; j < 4; ++j) {
            float l2a = fmaxf(si1 + sqj1[col + j] - 2.f * ax[j], 0.f);
            float l2b = fmaxf(si2 + sqj2[col + j] - 2.f * bx[j], 0.f);
            float t1 = __builtin_amdgcn_exp2f(-l2a * c1);
            float k1 = t1; float u1 = t1 * t1; k1 += u1; u1 *= u1; k1 += u1; u1 *= u1; k1 += u1; u1 *= u1; k1 += u1;
            float t2 = __builtin_amdgcn_exp2f(-l2b * c2);
            float k2 = t2; float u2 = t2 * t2; k2 += u2; u2 *= u2; k2 += u2; u2 *= u2; k2 += u2; u2 *= u2; k2 += u2;
            float v = k1 * k2;
            if (diag && (row == col + j)) v = 0.f;
            local += v;
        }
    }
    for (int o = 32; o; o >>= 1) local += __shfl_down(local, o);
    int lane = tid & 63, wv = tid >> 6;
    if (lane == 0) red[wv] = local;
    __syncthreads();
    if (tid == 0) {
        bool same = (i0 < BHALF) == (j0 < BHALF);
        float w = same ? (1.0f / ((float)BHALF * (float)(BHALF - 1)))
                       : (-1.0f / ((float)BHALF * (float)BHALF));
        if (!diag) w *= 2.f;
        atomicAdd(out, (red[0] + red[1] + red[2] + red[3]) * w);
    }
}

// ---------------- fallback: fused dual-GEMM (ws too small for Gram buffers) ------
__global__ __launch_bounds__(256, 2) void jmmd_fused(
    const uint8_t* __restrict__ t1f8, const uint8_t* __restrict__ t2f8,
    const float* __restrict__ sq1, const float* __restrict__ sq2,
    const float* __restrict__ cv, float* __restrict__ out) {
    __shared__ alignas(16) uint8_t smem[4][16384];
    __shared__ float sqi1[128], sqj1[128], sqi2[128], sqj2[128];
    __shared__ float red[4];
    int tid = threadIdx.x;
    int ti = 0, r = blockIdx.x;
    while (r >= TT - ti) { r -= TT - ti; ++ti; }
    int tj = ti + r;
    int i0 = ti * 128, j0 = tj * 128;
    if (tid < 128) {
        sqi1[tid] = sq1[i0 + tid]; sqj1[tid] = sq1[j0 + tid];
        sqi2[tid] = sq2[i0 + tid]; sqj2[tid] = sq2[j0 + tid];
    }
    int lane = tid & 63, wv = tid >> 6;
    int wm = wv >> 1, wn = wv & 1, lm = lane & 15, quad = lane >> 4;
    f32x4 acc1[4][4] = {};
    f32x4 acc2[4][4] = {};
    gemm_mx_pipe(t1f8 + (size_t)i0 * D1, t1f8 + (size_t)j0 * D1, D1,
                 smem[0], smem[1], smem[2], smem[3], acc1, wv, lane, wm, wn, lm, quad);
    // drain dummy prefetch + sync before re-priming the same buffers
    asm volatile("s_waitcnt vmcnt(0)\n\ts_barrier" ::: "memory");
    gemm_mx_pipe(t2f8 + (size_t)i0 * D2, t2f8 + (size_t)j0 * D2, D2,
                 smem[0], smem[1], smem[2], smem[3], acc2, wv, lane, wm, wn, lm, quad);
    float c1 = cv[0], c2 = cv[1];
    float local = 0.f;
    bool diag = (ti == tj);
#pragma unroll
    for (int mi = 0; mi < 4; ++mi) {
        int rbase = wm * 64 + mi * 16 + quad * 4;
#pragma unroll
        for (int ni = 0; ni < 4; ++ni) {
            int col = wn * 64 + ni * 16 + lm;
            float sb1 = sqj1[col], sb2 = sqj2[col];
#pragma unroll
            for (int rr = 0; rr < 4; ++rr) {
                int row = rbase + rr;
                float l2a = fmaxf(sqi1[row] + sb1 - 2.f * acc1[mi][ni][rr], 0.f);
                float l2b = fmaxf(sqi2[row] + sb2 - 2.f * acc2[mi][ni][rr], 0.f);
                float t1 = __builtin_amdgcn_exp2f(-l2a * c1);
                float k1 = t1; float u1 = t1 * t1; k1 += u1; u1 *= u1; k1 += u1; u1 *= u1; k1 += u1; u1 *= u1; k1 += u1;
                float t2 = __builtin_amdgcn_exp2f(-l2b * c2);
                float k2 = t2; float u2 = t2 * t2; k2 += u2; u2 *= u2; k2 += u2; u2 *= u2; k2 += u2; u2 *= u2; k2 += u2;
                float v = k1 * k2;
                if (diag && (row == col)) v = 0.f;
                local += v;
            }
        }
    }
    for (int o = 32; o; o >>= 1) local += __shfl_down(local, o);
    if (lane == 0) red[wv] = local;
    __syncthreads();
    if (tid == 0) {
        bool same = (i0 < BHALF) == (j0 < BHALF);
        float w = same ? (1.0f / ((float)BHALF * (float)(BHALF - 1)))
                       : (-1.0f / ((float)BHALF * (float)BHALF));
        if (!diag) w *= 2.f;
        atomicAdd(out, (red[0] + red[1] + red[2] + red[3]) * w);
    }
}

extern "C" void kernel_launch(void* const* d_in, const int* in_sizes, int n_in,
                              void* d_out, int out_size, void* d_ws, size_t ws_size,
                              hipStream_t stream) {
    const float* z1s = (const float*)d_in[0];
    const float* z1t = (const float*)d_in[1];
    const float* z2s = (const float*)d_in[2];
    const float* z2t = (const float*)d_in[3];
    float* out = (float*)d_out;

    float* ws = (float*)d_ws;
    float* sq1 = ws;              // 4096
    float* sq2 = ws + 4096;       // 4096
    float* s1  = ws + 8192;       // 4096
    float* s2  = ws + 12288;      // 2048
    float* acc = ws + 14336;      // [2]=c1 [3]=c2
    uint8_t* t1f8 = (uint8_t*)(ws + 14344);            // 16B-aligned
    uint8_t* t2f8 = t1f8 + (size_t)NTOT * D1;
    float* G1 = (float*)(t2f8 + (size_t)NTOT * D2);    // 16B-aligned
    float* G2 = G1 + (size_t)NTILES * 16384;
    size_t need_big = (size_t)14344 * 4
                    + ((size_t)NTOT * D1 + (size_t)NTOT * D2)
                    + (size_t)NTILES * 16384 * 2 * 4;

    prep_kernel<<<8192, 256, 0, stream>>>(z1s, z1t, z2s, z2t, sq1, sq2, t1f8, t2f8, s1, s2);
    colsum_fp8_kernel<<<384, 256, 0, stream>>>(t1f8, t2f8, s1, s2);
    finalize_kernel<<<1, 256, 0, stream>>>(s1, s2, sq1, sq2, acc, out);

    if (ws_size >= need_big) {
        gram_kernel<<<1056, 256, 0, stream>>>(t1f8, t2f8, G1, G2);
        epi_kernel<<<NTILES, 256, 0, stream>>>(G1, G2, sq1, sq2, acc + 2, out);
    } else {
        jmmd_fused<<<NTILES, 256, 0, stream>>>(t1f8, t2f8, sq1, sq2, acc + 2, out);
    }
}

// Round 8
// 277.295 us; speedup vs baseline: 1.7446x; 1.0616x over previous
//
#include <hip/hip_runtime.h>
#include <cstdint>

#define NTOT 4096   // 2b rows
#define BHALF 2048  // b
#define D1 4096
#define D2 2048
#define TT 32       // 4096/128 tiles per dim
#define NTILES 528  // TT*(TT+1)/2

typedef __attribute__((ext_vector_type(4))) float f32x4;
typedef __attribute__((ext_vector_type(4))) int i32x4;
typedef __attribute__((ext_vector_type(8))) int i32x8;

// async 16B global->LDS DMA (wave-uniform LDS base + lane*16 scatter)
__device__ __forceinline__ void glds16(const uint8_t* g, uint8_t* l) {
    __builtin_amdgcn_global_load_lds(
        (const __attribute__((address_space(1))) void*)(uintptr_t)g,
        (__attribute__((address_space(3))) void*)(uint32_t)(uintptr_t)l,
        16, 0, 0);
}

// raw LDS b128 read, opaque to the compiler's waitcnt insertion
__device__ __forceinline__ i32x4 ldsr(uint32_t addr) {
    i32x4 r;
    asm volatile("ds_read_b128 %0, %1" : "=v"(r) : "v"(addr));
    return r;
}

// e4m3fn decode (for colsum only; data never near NaN/448)
__device__ __forceinline__ float fp8dec(unsigned b) {
    unsigned e = (b >> 3) & 15u, m = b & 7u;
    float v = e ? __uint_as_float(((e + 120u) << 23) | (m << 20))
                : (float)m * 0.001953125f;   // subnormal: m * 2^-9
    return (b & 128u) ? -v : v;
}

// ---------------- prep: per-row sumsq (fp32) + fp8 e4m3 convert ----------------
__global__ void prep_kernel(const float* __restrict__ z1s, const float* __restrict__ z1t,
                            const float* __restrict__ z2s, const float* __restrict__ z2t,
                            float* __restrict__ sq1, float* __restrict__ sq2,
                            uint8_t* __restrict__ t1f8, uint8_t* __restrict__ t2f8,
                            float* __restrict__ s1, float* __restrict__ s2) {
    int bid = blockIdx.x;
    int tid = threadIdx.x;
    if (bid == 0) { for (int i = tid; i < 4096; i += 256) s1[i] = 0.f; }
    if (bid == 1) { for (int i = tid; i < 2048; i += 256) s2[i] = 0.f; }
    int which = bid >> 12;
    int row = bid & 4095;
    int d = which ? D2 : D1;
    const float* s_ = which ? z2s : z1s;
    const float* t_ = which ? z2t : z1t;
    const float* src = (row < BHALF) ? s_ + (size_t)row * d : t_ + (size_t)(row - BHALF) * d;
    uint8_t* dst = (which ? t2f8 : t1f8) + (size_t)row * d;
    float* sq = which ? sq2 : sq1;
    const float4* src4 = (const float4*)src;
    float a = 0.f;
    int n8 = d >> 3;
    for (int i = tid; i < n8; i += 256) {
        float4 v0 = src4[2 * i], v1 = src4[2 * i + 1];
        a += v0.x * v0.x + v0.y * v0.y + v0.z * v0.z + v0.w * v0.w;
        a += v1.x * v1.x + v1.y * v1.y + v1.z * v1.z + v1.w * v1.w;
        int w0 = __builtin_amdgcn_cvt_pk_fp8_f32(v0.x, v0.y, 0, 0);
        w0 = __builtin_amdgcn_cvt_pk_fp8_f32(v0.z, v0.w, w0, 1);
        int w1 = __builtin_amdgcn_cvt_pk_fp8_f32(v1.x, v1.y, 0, 0);
        w1 = __builtin_amdgcn_cvt_pk_fp8_f32(v1.z, v1.w, w1, 1);
        ((uint2*)dst)[i] = uint2{(unsigned)w0, (unsigned)w1};
    }
    for (int o = 32; o; o >>= 1) a += __shfl_down(a, o);
    __shared__ float sh[4];
    int lane = tid & 63, w = tid >> 6;
    if (lane == 0) sh[w] = a;
    __syncthreads();
    if (tid == 0) sq[row] = sh[0] + sh[1] + sh[2] + sh[3];
}

// ---------------- column sums from fp8 copies (bandwidth term only) ----------------
__global__ void colsum_fp8_kernel(const uint8_t* __restrict__ t1f8,
                                  const uint8_t* __restrict__ t2f8,
                                  float* __restrict__ s1, float* __restrict__ s2) {
    int bid = blockIdx.x;
    int which = bid >= 256;
    int local = which ? bid - 256 : bid;
    int d = which ? D2 : D1;
    int colchunks = d >> 10;
    int cb = local % colchunks, rb = local / colchunks;
    const uint8_t* base = which ? t2f8 : t1f8;
    float* s = which ? s2 : s1;
    int col = (cb << 10) + threadIdx.x * 4;
    int r0 = rb * 64;
    float a0 = 0.f, a1 = 0.f, a2 = 0.f, a3 = 0.f;
    const uint8_t* p = base + (size_t)r0 * d + col;
#pragma unroll 4
    for (int r = 0; r < 64; ++r) {
        uchar4 u = *(const uchar4*)(p + (size_t)r * d);
        a0 += fp8dec(u.x); a1 += fp8dec(u.y); a2 += fp8dec(u.z); a3 += fp8dec(u.w);
    }
    atomicAdd(&s[col], a0); atomicAdd(&s[col + 1], a1);
    atomicAdd(&s[col + 2], a2); atomicAdd(&s[col + 3], a3);
}

// ---------------- finalize: bandwidth constants + loss bias ----------------
__global__ void finalize_kernel(const float* __restrict__ s1, const float* __restrict__ s2,
                                const float* __restrict__ sq1, const float* __restrict__ sq2,
                                float* __restrict__ acc, float* __restrict__ out) {
    int tid = threadIdx.x;
    float a1 = 0.f, a2 = 0.f, q1 = 0.f, q2 = 0.f;
    for (int i = tid; i < 4096; i += 256) { float v = s1[i]; a1 += v * v; q1 += sq1[i]; q2 += sq2[i]; }
    for (int i = tid; i < 2048; i += 256) { float v = s2[i]; a2 += v * v; }
    for (int o = 32; o; o >>= 1) {
        a1 += __shfl_down(a1, o); a2 += __shfl_down(a2, o);
        q1 += __shfl_down(q1, o); q2 += __shfl_down(q2, o);
    }
    __shared__ float sh[4][4];
    int lane = tid & 63, w = tid >> 6;
    if (lane == 0) { sh[0][w] = a1; sh[1][w] = a2; sh[2][w] = q1; sh[3][w] = q2; }
    __syncthreads();
    if (tid == 0) {
        double ss1 = (double)sh[0][0] + sh[0][1] + sh[0][2] + sh[0][3];
        double ss2 = (double)sh[1][0] + sh[1][1] + sh[1][2] + sh[1][3];
        double t1 = (double)sh[2][0] + sh[2][1] + sh[2][2] + sh[2][3];
        double t2 = (double)sh[3][0] + sh[3][1] + sh[3][2] + sh[3][3];
        double S1 = 2.0 * (double)NTOT * t1 - 2.0 * ss1;
        double S2 = 2.0 * (double)NTOT * t2 - 2.0 * ss2;
        const double L2E = 1.4426950408889634;
        double nn = (double)NTOT * (double)(NTOT - 1);
        acc[2] = (float)(nn * L2E / (4.0 * S1));
        acc[3] = (float)(nn * L2E / (4.0 * S2));
        out[0] = 2.0f / (float)(BHALF - 1);
    }
}

// ---------------- pipelined MX-fp8 GEMM K-loop (R7-validated) ----------------
// Double-buffered LDS; prefetch issued BEFORE the barrier; raw s_barrier with
// manual s_waitcnt vmcnt(8) (prefetch stays in flight across the barrier).
// Frag reads via opaque asm ds_read_b128 + manual lgkmcnt(0). Second barrier
// (non-draining) covers the WAR on the buffer refilled next iteration.
// XOR chunk swizzle: logical 16B chunk c of row r at slot c^(r&7) — conflict-
// free reads, coalesced DMA within each 8-lane/128B group.
__device__ __forceinline__ void gemm_mx_pipe(const uint8_t* __restrict__ ga,
                                             const uint8_t* __restrict__ gb,
                                             int d,
                                             uint8_t* A0, uint8_t* B0,
                                             uint8_t* A1, uint8_t* B1,
                                             f32x4 (&acc)[4][4], int wv, int lane,
                                             int wm, int wn, int lm, int quad) {
    int nsteps = d >> 7;
    int rsub = lane >> 3;
    int ql = (lane & 7) ^ rsub;          // swizzled source chunk
    const uint8_t* pa = ga + (size_t)(wv * 32 + rsub) * d + ql * 16;
    const uint8_t* pb = gb + (size_t)(wv * 32 + rsub) * d + ql * 16;
    uint8_t* dA[2] = { A0 + wv * 4096, A1 + wv * 4096 };
    uint8_t* dB[2] = { B0 + wv * 4096, B1 + wv * 4096 };
    uint32_t baseA[2] = { (uint32_t)(uintptr_t)A0, (uint32_t)(uintptr_t)A1 };
    uint32_t baseB[2] = { (uint32_t)(uintptr_t)B0, (uint32_t)(uintptr_t)B1 };
    int s0 = ((2 * quad) ^ (lm & 7)) * 16;
    int s1 = ((2 * quad + 1) ^ (lm & 7)) * 16;
    uint32_t offA[4], offB[4];
#pragma unroll
    for (int i = 0; i < 4; ++i) {
        offA[i] = (uint32_t)((wm * 64 + i * 16 + lm) * 128);
        offB[i] = (uint32_t)((wn * 64 + i * 16 + lm) * 128);
    }
    // prime buffer 0 (k=0)
#pragma unroll
    for (int i = 0; i < 4; ++i) {
        glds16(pa + (size_t)i * 8 * d, dA[0] + i * 1024);
        glds16(pb + (size_t)i * 8 * d, dB[0] + i * 1024);
    }
    for (int k = 0; k < nsteps; ++k) {
        int cur = k & 1, nxt = cur ^ 1;
        size_t koff = (size_t)((k + 1 < nsteps) ? (k + 1) : 0) << 7;
#pragma unroll
        for (int i = 0; i < 4; ++i) {
            glds16(pa + koff + (size_t)i * 8 * d, dA[nxt] + i * 1024);
            glds16(pb + koff + (size_t)i * 8 * d, dB[nxt] + i * 1024);
        }
        asm volatile("s_waitcnt vmcnt(8)\n\ts_barrier" ::: "memory");
        i32x4 a00, a01, a10, a11, a20, a21, a30, a31;
        i32x4 b00, b01, b10, b11, b20, b21, b30, b31;
        a00 = ldsr(baseA[cur] + offA[0] + s0); a01 = ldsr(baseA[cur] + offA[0] + s1);
        a10 = ldsr(baseA[cur] + offA[1] + s0); a11 = ldsr(baseA[cur] + offA[1] + s1);
        a20 = ldsr(baseA[cur] + offA[2] + s0); a21 = ldsr(baseA[cur] + offA[2] + s1);
        a30 = ldsr(baseA[cur] + offA[3] + s0); a31 = ldsr(baseA[cur] + offA[3] + s1);
        b00 = ldsr(baseB[cur] + offB[0] + s0); b01 = ldsr(baseB[cur] + offB[0] + s1);
        b10 = ldsr(baseB[cur] + offB[1] + s0); b11 = ldsr(baseB[cur] + offB[1] + s1);
        b20 = ldsr(baseB[cur] + offB[2] + s0); b21 = ldsr(baseB[cur] + offB[2] + s1);
        b30 = ldsr(baseB[cur] + offB[3] + s0); b31 = ldsr(baseB[cur] + offB[3] + s1);
        asm volatile("s_waitcnt lgkmcnt(0)"
                     : "+v"(a00), "+v"(a01), "+v"(a10), "+v"(a11),
                       "+v"(a20), "+v"(a21), "+v"(a30), "+v"(a31),
                       "+v"(b00), "+v"(b01), "+v"(b10), "+v"(b11),
                       "+v"(b20), "+v"(b21), "+v"(b30), "+v"(b31));
        union F { i32x4 h[2]; i32x8 v; };
        F ua[4], ub[4];
        ua[0].h[0] = a00; ua[0].h[1] = a01; ua[1].h[0] = a10; ua[1].h[1] = a11;
        ua[2].h[0] = a20; ua[2].h[1] = a21; ua[3].h[0] = a30; ua[3].h[1] = a31;
        ub[0].h[0] = b00; ub[0].h[1] = b01; ub[1].h[0] = b10; ub[1].h[1] = b11;
        ub[2].h[0] = b20; ub[2].h[1] = b21; ub[3].h[0] = b30; ub[3].h[1] = b31;
#pragma unroll
        for (int ni = 0; ni < 4; ++ni)
#pragma unroll
            for (int mi = 0; mi < 4; ++mi)
                acc[mi][ni] = __builtin_amdgcn_mfma_scale_f32_16x16x128_f8f6f4(
                    ua[mi].v, ub[ni].v, acc[mi][ni], 0, 0, 0, 0x7F7F7F7F, 0, 0x7F7F7F7F);
        asm volatile("s_barrier" ::: "memory");
    }
}

// ---------------- fused dual-GEMM + kernel epilogue (no Gram materialization) ----
// Collapses R6/R7's gram+epi: removes 68 MB G-write + 103 MB G-read + 1 dispatch.
// Slot ledger R2 vs R3 showed split never improved GEMM slot rate — only aux.
__global__ __launch_bounds__(256, 2) void jmmd_fused(
    const uint8_t* __restrict__ t1f8, const uint8_t* __restrict__ t2f8,
    const float* __restrict__ sq1, const float* __restrict__ sq2,
    const float* __restrict__ cv, float* __restrict__ out) {
    __shared__ alignas(16) uint8_t smem[4][16384];   // A0,B0,A1,B1
    __shared__ float sqi1[128], sqj1[128], sqi2[128], sqj2[128];
    __shared__ float red[4];
    int tid = threadIdx.x;
    int ti = 0, r = blockIdx.x;
    while (r >= TT - ti) { r -= TT - ti; ++ti; }
    int tj = ti + r;
    int i0 = ti * 128, j0 = tj * 128;
    if (tid < 128) {
        sqi1[tid] = sq1[i0 + tid]; sqj1[tid] = sq1[j0 + tid];
        sqi2[tid] = sq2[i0 + tid]; sqj2[tid] = sq2[j0 + tid];
    }
    int lane = tid & 63, wv = tid >> 6;
    int wm = wv >> 1, wn = wv & 1, lm = lane & 15, quad = lane >> 4;
    f32x4 acc1[4][4] = {};
    f32x4 acc2[4][4] = {};
    gemm_mx_pipe(t1f8 + (size_t)i0 * D1, t1f8 + (size_t)j0 * D1, D1,
                 smem[0], smem[1], smem[2], smem[3], acc1, wv, lane, wm, wn, lm, quad);
    // drain dummy prefetch + sync before re-priming the same buffers
    asm volatile("s_waitcnt vmcnt(0)\n\ts_barrier" ::: "memory");
    gemm_mx_pipe(t2f8 + (size_t)i0 * D2, t2f8 + (size_t)j0 * D2, D2,
                 smem[0], smem[1], smem[2], smem[3], acc2, wv, lane, wm, wn, lm, quad);
    float c1 = cv[0], c2 = cv[1];
    float local = 0.f;
    bool diag = (ti == tj);
#pragma unroll
    for (int mi = 0; mi < 4; ++mi) {
        int rbase = wm * 64 + mi * 16 + quad * 4;
#pragma unroll
        for (int ni = 0; ni < 4; ++ni) {
            int col = wn * 64 + ni * 16 + lm;
            float sb1 = sqj1[col], sb2 = sqj2[col];
#pragma unroll
            for (int rr = 0; rr < 4; ++rr) {
                int row = rbase + rr;
                float l2a = fmaxf(sqi1[row] + sb1 - 2.f * acc1[mi][ni][rr], 0.f);
                float l2b = fmaxf(sqi2[row] + sb2 - 2.f * acc2[mi][ni][rr], 0.f);
                float t1 = __builtin_amdgcn_exp2f(-l2a * c1);
                float k1 = t1; float u1 = t1 * t1; k1 += u1; u1 *= u1; k1 += u1; u1 *= u1; k1 += u1; u1 *= u1; k1 += u1;
                float t2 = __builtin_amdgcn_exp2f(-l2b * c2);
                float k2 = t2; float u2 = t2 * t2; k2 += u2; u2 *= u2; k2 += u2; u2 *= u2; k2 += u2; u2 *= u2; k2 += u2;
                float v = k1 * k2;
                if (diag && (row == col)) v = 0.f;
                local += v;
            }
        }
    }
    for (int o = 32; o; o >>= 1) local += __shfl_down(local, o);
    if (lane == 0) red[wv] = local;
    __syncthreads();
    if (tid == 0) {
        bool same = (i0 < BHALF) == (j0 < BHALF);
        float w = same ? (1.0f / ((float)BHALF * (float)(BHALF - 1)))
                       : (-1.0f / ((float)BHALF * (float)BHALF));
        if (!diag) w *= 2.f;
        atomicAdd(out, (red[0] + red[1] + red[2] + red[3]) * w);
    }
}

extern "C" void kernel_launch(void* const* d_in, const int* in_sizes, int n_in,
                              void* d_out, int out_size, void* d_ws, size_t ws_size,
                              hipStream_t stream) {
    const float* z1s = (const float*)d_in[0];
    const float* z1t = (const float*)d_in[1];
    const float* z2s = (const float*)d_in[2];
    const float* z2t = (const float*)d_in[3];
    float* out = (float*)d_out;

    float* ws = (float*)d_ws;
    float* sq1 = ws;              // 4096
    float* sq2 = ws + 4096;       // 4096
    float* s1  = ws + 8192;       // 4096
    float* s2  = ws + 12288;      // 2048
    float* acc = ws + 14336;      // [2]=c1 [3]=c2
    uint8_t* t1f8 = (uint8_t*)(ws + 14344);            // 16B-aligned
    uint8_t* t2f8 = t1f8 + (size_t)NTOT * D1;

    prep_kernel<<<8192, 256, 0, stream>>>(z1s, z1t, z2s, z2t, sq1, sq2, t1f8, t2f8, s1, s2);
    colsum_fp8_kernel<<<384, 256, 0, stream>>>(t1f8, t2f8, s1, s2);
    finalize_kernel<<<1, 256, 0, stream>>>(s1, s2, sq1, sq2, acc, out);
    jmmd_fused<<<NTILES, 256, 0, stream>>>(t1f8, t2f8, sq1, sq2, acc + 2, out);
}